// Round 5
// baseline (765.491 us; speedup 1.0000x reference)
//
#include <hip/hip_runtime.h>
#include <math.h>

// ---------------- problem constants ----------------
#define GG   16      // stripes
#define KK   4       // latents per stripe
#define NN   64      // batch
#define CC   256     // channels
#define SHH  4       // stripe height
#define WW   44      // width
#define PP   176     // pixels per stripe
#define HWSZ 2816    // 64*44
#define CHW  720896  // CC*HWSZ
#define TOPKK 22     // int(176*0.125)

// ---------------- DPP wave64 ops (VALU pipe) ----------------
template<int CTRL, int RMASK>
__device__ __forceinline__ float dpp0(float v) {
    return __int_as_float(__builtin_amdgcn_update_dpp(
        0, __float_as_int(v), CTRL, RMASK, 0xF, true));
}
__device__ __forceinline__ float nbrL(float v) { return dpp0<0x138, 0xF>(v); } // wave_shr1
__device__ __forceinline__ float nbrR(float v) { return dpp0<0x130, 0xF>(v); } // wave_shl1

// sum of all 64 lanes; result valid on lane 63 only
__device__ __forceinline__ float wave_sum63(float v) {
    v += dpp0<0x111, 0xF>(v);
    v += dpp0<0x112, 0xF>(v);
    v += dpp0<0x114, 0xF>(v);
    v += dpp0<0x118, 0xF>(v);
    v += dpp0<0x142, 0xA>(v);   // bcast15 into rows 1,3
    v += dpp0<0x143, 0xC>(v);   // bcast31 into rows 2,3
    return v;
}
__device__ __forceinline__ float bcast63(float v) {
    return __int_as_float(__builtin_amdgcn_readlane(__float_as_int(v), 63));
}
__device__ __forceinline__ float wave_sum_all(float v) { return bcast63(wave_sum63(v)); }

// max over 64 lanes, broadcast; requires true max >= 0 (zero-fill safe)
__device__ __forceinline__ float wave_max_nn(float v) {
    v = fmaxf(v, dpp0<0x111, 0xF>(v));
    v = fmaxf(v, dpp0<0x112, 0xF>(v));
    v = fmaxf(v, dpp0<0x114, 0xF>(v));
    v = fmaxf(v, dpp0<0x118, 0xF>(v));
    v = fmaxf(v, dpp0<0x142, 0xA>(v));
    v = fmaxf(v, dpp0<0x143, 0xC>(v));
    return bcast63(v);
}

#define BPERM(a, x) __int_as_float(__builtin_amdgcn_ds_bpermute((a), __float_as_int(x)))

// One channel of 3x3-sum pooling + routing accumulation, float4 pixel layout.
// Lane l<44 owns pixels 4l..4l+3 (row l/11, cols 4*(l%11)..+3).
// Horizontal taps: in-register + DPP edge neighbors (masked pads).
// Vertical taps: ds_bpermute stride-11; pads come from lanes 44-63 whose h==0.
#define POOL_STEP(VV, CH) do {                                                 \
    const float4 lbv = lbn_lds[c0 + (CH)];                                     \
    fe4.x += VV.x * VV.x; fe4.y += VV.y * VV.y;                                \
    fe4.z += VV.z * VV.z; fe4.w += VV.w * VV.w;                                \
    const float Lv = lmask * nbrL(VV.w);                                       \
    const float Rv = rmask * nbrR(VV.x);                                       \
    float4 h;                                                                  \
    h.x = Lv + VV.x + VV.y;                                                    \
    h.y = VV.x + VV.y + VV.z;                                                  \
    h.z = VV.y + VV.z + VV.w;                                                  \
    h.w = VV.z + VV.w + Rv;                                                    \
    float4 p;                                                                  \
    p.x = h.x + BPERM(addr_up, h.x) + BPERM(addr_dn, h.x);                     \
    p.y = h.y + BPERM(addr_up, h.y) + BPERM(addr_dn, h.y);                     \
    p.z = h.z + BPERM(addr_up, h.z) + BPERM(addr_dn, h.z);                     \
    p.w = h.w + BPERM(addr_up, h.w) + BPERM(addr_dn, h.w);                     \
    nr4.x += p.x * p.x; nr4.y += p.y * p.y;                                    \
    nr4.z += p.z * p.z; nr4.w += p.w * p.w;                                    \
    dk[0].x += p.x * lbv.x; dk[0].y += p.y * lbv.x;                            \
    dk[0].z += p.z * lbv.x; dk[0].w += p.w * lbv.x;                            \
    dk[1].x += p.x * lbv.y; dk[1].y += p.y * lbv.y;                            \
    dk[1].z += p.z * lbv.y; dk[1].w += p.w * lbv.y;                            \
    dk[2].x += p.x * lbv.z; dk[2].y += p.y * lbv.z;                            \
    dk[2].z += p.z * lbv.z; dk[2].w += p.w * lbv.z;                            \
    dk[3].x += p.x * lbv.w; dk[3].y += p.y * lbv.w;                            \
    dk[3].z += p.z * lbv.w; dk[3].w += p.w * lbv.w;                            \
} while (0)

// ---------------- fused routing + token kernel ----------------
// grid (GG, NN), 512 threads = 8 waves; wave w owns channels [w*32, w*32+32).
// Phase 1: float4-per-lane 3x3 pooling (DPP horizontal, bpermute vertical),
// depth-4 channel prefetch; LDS cross-wave reduction; finalize (+pwT build);
// topk (waves 0-3) parallel with scatter (waves 4-7).
// Phase 2: fused token pass, same float4 pixel layout, depth-3 prefetch.
__global__ __launch_bounds__(512, 8) void routing_kernel(
    const float* __restrict__ x, const float* __restrict__ lb_raw,
    float* __restrict__ pres_ws,
    float4* __restrict__ outS, float4* __restrict__ outP,
    float* __restrict__ tok_out) {
    const int g = blockIdx.x;
    const int n = blockIdx.y;
    const int tid = threadIdx.x;
    const int w = __builtin_amdgcn_readfirstlane(tid >> 6);
    const int lane = tid & 63;
    const bool al = lane < WW;

    __shared__ float4 pd[8][PP];     // per-wave d partials; pd[0] -> sum
    __shared__ float2 pnf[8][PP];    // (nrm, fe) partials; pnf[0] -> sum
    __shared__ float4 lbn_lds[CC];   // [c] -> float4 over k, scaled by 1/9
    __shared__ float redA[4], redB[4], zred[4][4];
    float4* sup4 = pd[2];            // reused after reduction
    float4* pw4  = pd[4];
    float4* pwT  = pd[6];            // pw transposed: pwT[j*44+l4] = pw[4*l4+j]

    // ---- basis norm: wave k (0..3) normalizes latent (g,k) into LDS ----
    if (w < 4) {
        const float* row = lb_raw + ((size_t)g * KK + w) * CC;
        float v0 = row[lane], v1 = row[lane + 64], v2 = row[lane + 128], v3 = row[lane + 192];
        float ss = v0 * v0 + v1 * v1 + v2 * v2 + v3 * v3;
        float tot = wave_sum_all(ss);
        float sc = (1.0f / 9.0f) / fmaxf(sqrtf(tot), 1e-12f);
        float* dst = (float*)lbn_lds;
        dst[lane * 4 + w]         = v0 * sc;
        dst[(lane + 64) * 4 + w]  = v1 * sc;
        dst[(lane + 128) * 4 + w] = v2 * sc;
        dst[(lane + 192) * 4 + w] = v3 * sc;
    }
    __syncthreads();

    const float* xb = x + (size_t)n * CHW + g * PP;
    const int c0 = w * 32;

    // ---- main loop: float4 pixel layout, depth-4 prefetch ----
    const int rr = lane / 11;                       // stripe row (lane<44)
    const int mm = lane - rr * 11;                  // col group
    const float lmask = (al && mm != 0)  ? 1.0f : 0.0f;
    const float rmask = (al && mm != 10) ? 1.0f : 0.0f;
    // vertical neighbor lanes; pads route to lanes 44-63 (h==0 there)
    const int addr_up = ((lane < 11) ? (lane + 44) : (lane - 11)) * 4;
    const int addr_dn = (lane + 11) * 4;

    float4 dk[4];
    #pragma unroll
    for (int s = 0; s < 4; ++s) dk[s] = make_float4(0, 0, 0, 0);
    float4 nr4 = make_float4(0, 0, 0, 0);
    float4 fe4 = make_float4(0, 0, 0, 0);

    const float4* xp4 = (const float4*)(xb + (size_t)c0 * HWSZ) + lane;  // ch stride 704
    float4 sA = make_float4(0, 0, 0, 0), sB = sA, sC = sA, sD = sA;
    if (al) { sA = xp4[0]; sB = xp4[704]; sC = xp4[1408]; sD = xp4[2112]; }

    #pragma unroll 1
    for (int i = 0; i < 32; i += 4) {
        POOL_STEP(sA, i + 0);
        if (i < 28 && al) sA = xp4[(size_t)(i + 4) * 704];
        POOL_STEP(sB, i + 1);
        if (i < 28 && al) sB = xp4[(size_t)(i + 5) * 704];
        POOL_STEP(sC, i + 2);
        if (i < 28 && al) sC = xp4[(size_t)(i + 6) * 704];
        POOL_STEP(sD, i + 3);
        if (i < 28 && al) sD = xp4[(size_t)(i + 7) * 704];
    }

    if (al) {
        const int p0 = lane * 4;    // absolute pixel of component .x
        pd[w][p0 + 0] = make_float4(dk[0].x, dk[1].x, dk[2].x, dk[3].x);
        pd[w][p0 + 1] = make_float4(dk[0].y, dk[1].y, dk[2].y, dk[3].y);
        pd[w][p0 + 2] = make_float4(dk[0].z, dk[1].z, dk[2].z, dk[3].z);
        pd[w][p0 + 3] = make_float4(dk[0].w, dk[1].w, dk[2].w, dk[3].w);
        pnf[w][p0 + 0] = make_float2(nr4.x, fe4.x);
        pnf[w][p0 + 1] = make_float2(nr4.y, fe4.y);
        pnf[w][p0 + 2] = make_float2(nr4.z, fe4.z);
        pnf[w][p0 + 3] = make_float2(nr4.w, fe4.w);
    }
    __syncthreads();

    // ---- cross-wave reduction into slot 0 ----
    if (tid < PP) {
        float4 a = pd[0][tid];
        #pragma unroll
        for (int ww = 1; ww < 8; ++ww) {
            float4 b = pd[ww][tid];
            a.x += b.x; a.y += b.y; a.z += b.z; a.w += b.w;
        }
        pd[0][tid] = a;
    } else if (tid >= 256 && tid < 256 + PP) {
        const int p = tid - 256;
        float2 a = pnf[0][p];
        #pragma unroll
        for (int ww = 1; ww < 8; ++ww) {
            float2 b = pnf[ww][p];
            a.x += b.x; a.y += b.y;
        }
        pnf[0][p] = a;
    }
    __syncthreads();

    // ---- finalize (8 waves redundant; waves 0..3 write) ----
    const int s4 = w & 3;
    const int pix = s4 * 44 + (al ? lane : 0);
    float4 dv = pd[0][pix];
    float2 nf = pnf[0][pix];
    float nrm = nf.x;
    float fev = nf.y * (1.0f / 256.0f);

    float fmw = wave_max_nn(al ? fev : 0.0f);
    if (w < 4 && lane == 0) redA[s4] = fmw;
    __syncthreads();
    float femax = fmaxf(fmaxf(redA[0], redA[1]), fmaxf(redA[2], redA[3]));
    float den = fmaxf(femax, 1e-6f);
    bool pa = al && ((fev / den) > 0.05f);
    unsigned long long bl = __ballot((int)pa);
    if (w < 4 && lane == 0) redB[s4] = (float)__popcll(bl);
    __syncthreads();
    float cnt = redB[0] + redB[1] + redB[2] + redB[3];
    float actv = pa ? 1.0f : 0.0f;
    if (cnt <= 0.0f) actv = (al && (fev > 0.0f)) ? 1.0f : 0.0f;

    float inv = 72.0f / fmaxf(sqrtf(nrm), 9e-12f);   // 8/TEMP on raw 3x3 sums
    float L0 = dv.x * inv, L1 = dv.y * inv, L2 = dv.z * inv, L3 = dv.w * inv;
    float mx = fmaxf(fmaxf(L0, L1), fmaxf(L2, L3));
    float e0 = expf(L0 - mx), e1 = expf(L1 - mx), e2 = expf(L2 - mx), e3 = expf(L3 - mx);
    float esum = e0 + e1 + e2 + e3;
    float sc = actv / esum;
    float s0 = e0 * sc, s1 = e1 * sc, s2 = e2 * sc, s3 = e3 * sc;

    float z0 = wave_sum63(s0), z1 = wave_sum63(s1), z2 = wave_sum63(s2), z3 = wave_sum63(s3);
    if (w < 4 && lane == 63) { zred[s4][0] = z0; zred[s4][1] = z1; zred[s4][2] = z2; zred[s4][3] = z3; }
    __syncthreads();
    float Z0 = zred[0][0] + zred[1][0] + zred[2][0] + zred[3][0];
    float Z1 = zred[0][1] + zred[1][1] + zred[2][1] + zred[3][1];
    float Z2 = zred[0][2] + zred[1][2] + zred[2][2] + zred[3][2];
    float Z3 = zred[0][3] + zred[1][3] + zred[2][3] + zred[3][3];
    float q0 = s0 / fmaxf(Z0, 1e-6f);
    float q1 = s1 / fmaxf(Z1, 1e-6f);
    float q2 = s2 / fmaxf(Z2, 1e-6f);
    float q3 = s3 / fmaxf(Z3, 1e-6f);

    if (w < 4 && al) {
        float4 qv = make_float4(q0, q1, q2, q3);
        sup4[pix] = make_float4(s0, s1, s2, s3);
        pw4[pix]  = qv;
        pwT[(pix & 3) * 44 + (pix >> 2)] = qv;   // transpose for token phase
    }
    __syncthreads();
    // After this barrier sup4/pw4/pwT are final; everything below only READS
    // them, so no further __syncthreads is required.

    // ---- top-22 presence: waves 0..3; waves 4..7 do the full scatter ----
    if (w < 4) {
        const float* supf = (const float*)sup4;
        const int k = w;
        float v0 = supf[lane * 4 + k];
        float v1 = supf[(lane + 64) * 4 + k];
        float v2 = (lane < PP - 128) ? supf[(lane + 128) * 4 + k] : -1e30f;
        float tks = 0.0f;
        for (int it = 0; it < TOPKK; ++it) {
            float lm = fmaxf(v0, fmaxf(v1, v2));
            float M = wave_max_nn(lm);
            tks += M;
            unsigned long long mk = __ballot((int)(lm == M));
            int src = __ffsll(mk) - 1;
            if (lane == src) {
                if (v0 == M)      v0 = -1e30f;
                else if (v1 == M) v1 = -1e30f;
                else              v2 = -1e30f;
            }
        }
        if (lane == 0) pres_ws[(size_t)n * 64 + g * KK + k] = tks * (1.0f / (float)TOPKK);
    } else {
        // ---- direct scatter: block owns output pixels [g*176, g*176+176) ----
        const size_t obase = ((size_t)n * HWSZ + (size_t)g * PP) * 16;
        const float4 z = make_float4(0, 0, 0, 0);
        const int t0i = tid - 256;   // 0..255, PP*16/256 = 11 iters
        #pragma unroll 1
        for (int m = 0; m < 11; ++m) {
            const int j = t0i + m * 256;
            const int px = j >> 4, q = j & 15;
            const bool hit = (q == g);
            outS[obase + j] = hit ? sup4[px] : z;
            outP[obase + j] = hit ? pw4[px]  : z;
        }
    }

    // ---- fused token phase: wave w reduces tokens for channels [c0, c0+32) ----
    // lane l<44 owns pixels 4l..4l+3 as one float4; pw pre-transposed in pwT.
    // In-loop prefetch depth 3; x re-read is L3-hot.
    {
        float4 pwa = make_float4(0, 0, 0, 0), pwb = pwa, pwc = pwa, pwd = pwa;
        if (al) {
            pwa = pwT[lane];        // pw of pixel 4l+0
            pwb = pwT[44 + lane];   // 4l+1
            pwc = pwT[88 + lane];   // 4l+2
            pwd = pwT[132 + lane];  // 4l+3
        }
        const float4* xq4 = (const float4*)(xb + (size_t)c0 * HWSZ) + lane;
        float4 tA = make_float4(0, 0, 0, 0), tB = tA, tC = tA;
        if (al) { tA = xq4[0]; tB = xq4[704]; tC = xq4[1408]; }
        xq4 += 3 * 704;
        float* tokg = tok_out + ((size_t)n * CC + c0) * 64 + g * KK;

        #pragma unroll 1
        for (int i = 0; i < 32; ++i) {
            float4 tF = make_float4(0, 0, 0, 0);
            if (i < 29 && al) tF = xq4[0];
            xq4 += 704;
            float t0 = tA.x * pwa.x + tA.y * pwb.x + tA.z * pwc.x + tA.w * pwd.x;
            float t1 = tA.x * pwa.y + tA.y * pwb.y + tA.z * pwc.y + tA.w * pwd.y;
            float t2 = tA.x * pwa.z + tA.y * pwb.z + tA.z * pwc.z + tA.w * pwd.z;
            float t3 = tA.x * pwa.w + tA.y * pwb.w + tA.z * pwc.w + tA.w * pwd.w;
            t0 = wave_sum63(t0); t1 = wave_sum63(t1); t2 = wave_sum63(t2); t3 = wave_sum63(t3);
            if (lane == 63) {
                *(float4*)(tokg + (size_t)i * 64) = make_float4(t0, t1, t2, t3);
            }
            tA = tB; tB = tC; tC = tF;
        }
    }
}

// ---------------- presence normalization ----------------
__global__ __launch_bounds__(64) void presence_kernel(
    const float* __restrict__ pres_ws, float* __restrict__ outp) {
    const int n = blockIdx.x;
    const int lane = threadIdx.x;
    float v = pres_ws[(size_t)n * 64 + lane];
    float tot = wave_sum_all(v);
    outp[(size_t)n * 64 + lane] = v / fmaxf(tot, 1e-6f);
}

// ---------------- launch ----------------
extern "C" void kernel_launch(void* const* d_in, const int* in_sizes, int n_in,
                              void* d_out, int out_size, void* d_ws, size_t ws_size,
                              hipStream_t stream) {
    const float* x = (const float*)d_in[0];        // [64,256,64,44]
    const float* lb = (const float*)d_in[1];       // [16,4,256]
    float* ws = (float*)d_ws;
    float* pres_ws = ws;                            // 4096 floats

    float* out = (float*)d_out;
    float* tok  = out;                     // [64,256,64]
    float* pres = out + 1048576;           // [64,64]
    float* outS = out + 1052672;           // [64,2816,64]
    float* outP = outS + 11534336;         // [64,2816,64]

    routing_kernel<<<dim3(GG, NN), 512, 0, stream>>>(
        x, lb, pres_ws, (float4*)outS, (float4*)outP, tok);
    presence_kernel<<<NN, 64, 0, stream>>>(pres_ws, pres);
}

// Round 6
// 335.377 us; speedup vs baseline: 2.2825x; 2.2825x over previous
//
#include <hip/hip_runtime.h>
#include <math.h>

// ---------------- problem constants ----------------
#define GG   16      // stripes
#define KK   4       // latents per stripe
#define NN   64      // batch
#define CC   256     // channels
#define SHH  4       // stripe height
#define WW   44      // width
#define PP   176     // pixels per stripe
#define HWSZ 2816    // 64*44
#define CHW  720896  // CC*HWSZ
#define TOPKK 22     // int(176*0.125)

// ---------------- DPP wave64 ops (VALU pipe) ----------------
template<int CTRL, int RMASK>
__device__ __forceinline__ float dpp0(float v) {
    return __int_as_float(__builtin_amdgcn_update_dpp(
        0, __float_as_int(v), CTRL, RMASK, 0xF, true));
}
__device__ __forceinline__ float nbrL(float v) { return dpp0<0x138, 0xF>(v); } // wave_shr1
__device__ __forceinline__ float nbrR(float v) { return dpp0<0x130, 0xF>(v); } // wave_shl1

// sum of all 64 lanes; result valid on lane 63 only
__device__ __forceinline__ float wave_sum63(float v) {
    v += dpp0<0x111, 0xF>(v);
    v += dpp0<0x112, 0xF>(v);
    v += dpp0<0x114, 0xF>(v);
    v += dpp0<0x118, 0xF>(v);
    v += dpp0<0x142, 0xA>(v);   // bcast15 into rows 1,3
    v += dpp0<0x143, 0xC>(v);   // bcast31 into rows 2,3
    return v;
}
__device__ __forceinline__ float bcast63(float v) {
    return __int_as_float(__builtin_amdgcn_readlane(__float_as_int(v), 63));
}
__device__ __forceinline__ float wave_sum_all(float v) { return bcast63(wave_sum63(v)); }

// max over 64 lanes, broadcast; requires true max >= 0 (zero-fill safe)
__device__ __forceinline__ float wave_max_nn(float v) {
    v = fmaxf(v, dpp0<0x111, 0xF>(v));
    v = fmaxf(v, dpp0<0x112, 0xF>(v));
    v = fmaxf(v, dpp0<0x114, 0xF>(v));
    v = fmaxf(v, dpp0<0x118, 0xF>(v));
    v = fmaxf(v, dpp0<0x142, 0xA>(v));
    v = fmaxf(v, dpp0<0x143, 0xC>(v));
    return bcast63(v);
}

// ---------------- fused routing + token kernel ----------------
// grid (GG, NN), 512 threads = 8 waves; wave w owns channels [w*32, w*32+32).
// Phase 1: register 3x3 pooling via DPP (scalar column-per-lane layout —
// round-4 verified; float4 layout spills to scratch under the 64-VGPR cap),
// prefetch depth 3; one LDS cross-wave reduction; finalize (+pwT build);
// topk (waves 0-3) parallel with scatter (waves 4-7).
// Phase 2: fused token pass, float4 pixel layout, in-loop depth-3 prefetch.
__global__ __launch_bounds__(512, 8) void routing_kernel(
    const float* __restrict__ x, const float* __restrict__ lb_raw,
    float* __restrict__ pres_ws,
    float4* __restrict__ outS, float4* __restrict__ outP,
    float* __restrict__ tok_out) {
    const int g = blockIdx.x;
    const int n = blockIdx.y;
    const int tid = threadIdx.x;
    const int w = __builtin_amdgcn_readfirstlane(tid >> 6);
    const int lane = tid & 63;
    const bool al = lane < WW;

    __shared__ float4 pd[8][PP];     // per-wave d partials; pd[0] -> sum
    __shared__ float2 pnf[8][PP];    // (nrm, fe) partials; pnf[0] -> sum
    __shared__ float4 lbn_lds[CC];   // [c] -> float4 over k, scaled by 1/9
    __shared__ float redA[4], redB[4], zred[4][4];
    float4* sup4 = pd[2];            // reused after reduction
    float4* pw4  = pd[4];
    float4* pwT  = pd[6];            // pw transposed: pwT[j*44+l4] = pw[4*l4+j]

    // ---- basis norm: wave k (0..3) normalizes latent (g,k) into LDS ----
    if (w < 4) {
        const float* row = lb_raw + ((size_t)g * KK + w) * CC;
        float v0 = row[lane], v1 = row[lane + 64], v2 = row[lane + 128], v3 = row[lane + 192];
        float ss = v0 * v0 + v1 * v1 + v2 * v2 + v3 * v3;
        float tot = wave_sum_all(ss);
        float sc = (1.0f / 9.0f) / fmaxf(sqrtf(tot), 1e-12f);
        float* dst = (float*)lbn_lds;
        dst[lane * 4 + w]         = v0 * sc;
        dst[(lane + 64) * 4 + w]  = v1 * sc;
        dst[(lane + 128) * 4 + w] = v2 * sc;
        dst[(lane + 192) * 4 + w] = v3 * sc;
    }
    __syncthreads();

    const float* xb = x + (size_t)n * CHW + g * PP;
    const int c0 = w * 32;

    float4 dk[4];
    float nr[4] = {0, 0, 0, 0}, fe[4] = {0, 0, 0, 0};
    #pragma unroll
    for (int s = 0; s < 4; ++s) dk[s] = make_float4(0, 0, 0, 0);

    // prefetch depth 3: channels i (cur), i+1, i+2 in flight
    const float* xp = xb + (size_t)c0 * HWSZ + lane;
    float c0r = 0, c1r = 0, c2r = 0, c3r = 0;
    float n0r = 0, n1r = 0, n2r = 0, n3r = 0;
    float m0r = 0, m1r = 0, m2r = 0, m3r = 0;
    if (al) {
        c0r = xp[0]; c1r = xp[44]; c2r = xp[88]; c3r = xp[132];
        n0r = xp[HWSZ]; n1r = xp[HWSZ + 44]; n2r = xp[HWSZ + 88]; n3r = xp[HWSZ + 132];
        m0r = xp[2 * HWSZ]; m1r = xp[2 * HWSZ + 44]; m2r = xp[2 * HWSZ + 88]; m3r = xp[2 * HWSZ + 132];
    }
    xp += 3 * HWSZ;
    #pragma unroll 1
    for (int i = 0; i < 32; ++i) {
        float f0 = 0, f1 = 0, f2 = 0, f3 = 0;
        if (i < 29 && al) { f0 = xp[0]; f1 = xp[44]; f2 = xp[88]; f3 = xp[132]; }
        xp += HWSZ;
        float4 lbv = lbn_lds[c0 + i];   // wave-uniform -> LDS broadcast
        fe[0] += c0r * c0r; fe[1] += c1r * c1r; fe[2] += c2r * c2r; fe[3] += c3r * c3r;
        float h0 = c0r + nbrL(c0r) + nbrR(c0r);
        float h1 = c1r + nbrL(c1r) + nbrR(c1r);
        float h2 = c2r + nbrL(c2r) + nbrR(c2r);
        float h3 = c3r + nbrL(c3r) + nbrR(c3r);
        // raw 3x3 sums (1/9 folded into lbv; nrm fixed via inv=72/sqrt)
        float p0 = h0 + h1;          // row -1 zero pad
        float p1 = p0 + h2;
        float t23 = h2 + h3;
        float p2 = h1 + t23;
        float p3 = t23;              // row 4 zero pad
        nr[0] += p0 * p0; nr[1] += p1 * p1; nr[2] += p2 * p2; nr[3] += p3 * p3;
        dk[0].x += p0 * lbv.x; dk[0].y += p0 * lbv.y; dk[0].z += p0 * lbv.z; dk[0].w += p0 * lbv.w;
        dk[1].x += p1 * lbv.x; dk[1].y += p1 * lbv.y; dk[1].z += p1 * lbv.z; dk[1].w += p1 * lbv.w;
        dk[2].x += p2 * lbv.x; dk[2].y += p2 * lbv.y; dk[2].z += p2 * lbv.z; dk[2].w += p2 * lbv.w;
        dk[3].x += p3 * lbv.x; dk[3].y += p3 * lbv.y; dk[3].z += p3 * lbv.z; dk[3].w += p3 * lbv.w;
        c0r = n0r; c1r = n1r; c2r = n2r; c3r = n3r;
        n0r = m0r; n1r = m1r; n2r = m2r; n3r = m3r;
        m0r = f0; m1r = f1; m2r = f2; m3r = f3;
    }
    if (al) {
        #pragma unroll
        for (int s = 0; s < 4; ++s) {
            pd[w][s * 44 + lane]  = dk[s];
            pnf[w][s * 44 + lane] = make_float2(nr[s], fe[s]);
        }
    }
    __syncthreads();

    // ---- cross-wave reduction into slot 0 ----
    if (tid < PP) {
        float4 a = pd[0][tid];
        #pragma unroll
        for (int ww = 1; ww < 8; ++ww) {
            float4 b = pd[ww][tid];
            a.x += b.x; a.y += b.y; a.z += b.z; a.w += b.w;
        }
        pd[0][tid] = a;
    } else if (tid >= 256 && tid < 256 + PP) {
        const int p = tid - 256;
        float2 a = pnf[0][p];
        #pragma unroll
        for (int ww = 1; ww < 8; ++ww) {
            float2 b = pnf[ww][p];
            a.x += b.x; a.y += b.y;
        }
        pnf[0][p] = a;
    }
    __syncthreads();

    // ---- finalize (8 waves redundant; waves 0..3 write) ----
    const int s4 = w & 3;
    const int pix = s4 * 44 + (al ? lane : 0);
    float4 dv = pd[0][pix];
    float2 nf = pnf[0][pix];
    float nrm = nf.x;
    float fev = nf.y * (1.0f / 256.0f);

    float fmw = wave_max_nn(al ? fev : 0.0f);
    if (w < 4 && lane == 0) redA[s4] = fmw;
    __syncthreads();
    float femax = fmaxf(fmaxf(redA[0], redA[1]), fmaxf(redA[2], redA[3]));
    float den = fmaxf(femax, 1e-6f);
    bool pa = al && ((fev / den) > 0.05f);
    unsigned long long bl = __ballot((int)pa);
    if (w < 4 && lane == 0) redB[s4] = (float)__popcll(bl);
    __syncthreads();
    float cnt = redB[0] + redB[1] + redB[2] + redB[3];
    float actv = pa ? 1.0f : 0.0f;
    if (cnt <= 0.0f) actv = (al && (fev > 0.0f)) ? 1.0f : 0.0f;

    float inv = 72.0f / fmaxf(sqrtf(nrm), 9e-12f);   // 8/TEMP on raw 3x3 sums
    float L0 = dv.x * inv, L1 = dv.y * inv, L2 = dv.z * inv, L3 = dv.w * inv;
    float mx = fmaxf(fmaxf(L0, L1), fmaxf(L2, L3));
    float e0 = expf(L0 - mx), e1 = expf(L1 - mx), e2 = expf(L2 - mx), e3 = expf(L3 - mx);
    float esum = e0 + e1 + e2 + e3;
    float sc = actv / esum;
    float s0 = e0 * sc, s1 = e1 * sc, s2 = e2 * sc, s3 = e3 * sc;

    float z0 = wave_sum63(s0), z1 = wave_sum63(s1), z2 = wave_sum63(s2), z3 = wave_sum63(s3);
    if (w < 4 && lane == 63) { zred[s4][0] = z0; zred[s4][1] = z1; zred[s4][2] = z2; zred[s4][3] = z3; }
    __syncthreads();
    float Z0 = zred[0][0] + zred[1][0] + zred[2][0] + zred[3][0];
    float Z1 = zred[0][1] + zred[1][1] + zred[2][1] + zred[3][1];
    float Z2 = zred[0][2] + zred[1][2] + zred[2][2] + zred[3][2];
    float Z3 = zred[0][3] + zred[1][3] + zred[2][3] + zred[3][3];
    float q0 = s0 / fmaxf(Z0, 1e-6f);
    float q1 = s1 / fmaxf(Z1, 1e-6f);
    float q2 = s2 / fmaxf(Z2, 1e-6f);
    float q3 = s3 / fmaxf(Z3, 1e-6f);

    if (w < 4 && al) {
        float4 qv = make_float4(q0, q1, q2, q3);
        sup4[pix] = make_float4(s0, s1, s2, s3);
        pw4[pix]  = qv;
        pwT[(pix & 3) * 44 + (pix >> 2)] = qv;   // transpose for token phase
    }
    __syncthreads();
    // After this barrier sup4/pw4/pwT are final; everything below only READS
    // them, so no further __syncthreads is required.

    // ---- top-22 presence: waves 0..3; waves 4..7 do the full scatter ----
    if (w < 4) {
        const float* supf = (const float*)sup4;
        const int k = w;
        float v0 = supf[lane * 4 + k];
        float v1 = supf[(lane + 64) * 4 + k];
        float v2 = (lane < PP - 128) ? supf[(lane + 128) * 4 + k] : -1e30f;
        float tks = 0.0f;
        for (int it = 0; it < TOPKK; ++it) {
            float lm = fmaxf(v0, fmaxf(v1, v2));
            float M = wave_max_nn(lm);
            tks += M;
            unsigned long long mk = __ballot((int)(lm == M));
            int src = __ffsll(mk) - 1;
            if (lane == src) {
                if (v0 == M)      v0 = -1e30f;
                else if (v1 == M) v1 = -1e30f;
                else              v2 = -1e30f;
            }
        }
        if (lane == 0) pres_ws[(size_t)n * 64 + g * KK + k] = tks * (1.0f / (float)TOPKK);
    } else {
        // ---- direct scatter: block owns output pixels [g*176, g*176+176) ----
        const size_t obase = ((size_t)n * HWSZ + (size_t)g * PP) * 16;
        const float4 z = make_float4(0, 0, 0, 0);
        const int t0i = tid - 256;   // 0..255, PP*16/256 = 11 iters
        #pragma unroll 1
        for (int m = 0; m < 11; ++m) {
            const int j = t0i + m * 256;
            const int px = j >> 4, q = j & 15;
            const bool hit = (q == g);
            outS[obase + j] = hit ? sup4[px] : z;
            outP[obase + j] = hit ? pw4[px]  : z;
        }
    }

    // ---- fused token phase: wave w reduces tokens for channels [c0, c0+32) ----
    // lane l<44 owns pixels 4l..4l+3 as one float4; pw pre-transposed in pwT.
    // In-loop prefetch depth 3; x re-read is L3-hot (this block streamed it
    // in phase 1).
    {
        const bool a4 = lane < 44;
        float4 pwa = make_float4(0, 0, 0, 0), pwb = pwa, pwc = pwa, pwd = pwa;
        if (a4) {
            pwa = pwT[lane];        // pw of pixel 4l+0
            pwb = pwT[44 + lane];   // 4l+1
            pwc = pwT[88 + lane];   // 4l+2
            pwd = pwT[132 + lane];  // 4l+3
        }
        const float4* xq4 = (const float4*)(xb + (size_t)c0 * HWSZ) + lane;
        float4 tA = make_float4(0, 0, 0, 0), tB = tA, tC = tA;
        if (a4) { tA = xq4[0]; tB = xq4[704]; tC = xq4[1408]; }
        xq4 += 3 * 704;
        float* tokg = tok_out + ((size_t)n * CC + c0) * 64 + g * KK;

        #pragma unroll 1
        for (int i = 0; i < 32; ++i) {
            float4 tF = make_float4(0, 0, 0, 0);
            if (i < 29 && a4) tF = xq4[0];
            xq4 += 704;
            float t0 = tA.x * pwa.x + tA.y * pwb.x + tA.z * pwc.x + tA.w * pwd.x;
            float t1 = tA.x * pwa.y + tA.y * pwb.y + tA.z * pwc.y + tA.w * pwd.y;
            float t2 = tA.x * pwa.z + tA.y * pwb.z + tA.z * pwc.z + tA.w * pwd.z;
            float t3 = tA.x * pwa.w + tA.y * pwb.w + tA.z * pwc.w + tA.w * pwd.w;
            t0 = wave_sum63(t0); t1 = wave_sum63(t1); t2 = wave_sum63(t2); t3 = wave_sum63(t3);
            if (lane == 63) {
                *(float4*)(tokg + (size_t)i * 64) = make_float4(t0, t1, t2, t3);
            }
            tA = tB; tB = tC; tC = tF;
        }
    }
}

// ---------------- presence normalization ----------------
__global__ __launch_bounds__(64) void presence_kernel(
    const float* __restrict__ pres_ws, float* __restrict__ outp) {
    const int n = blockIdx.x;
    const int lane = threadIdx.x;
    float v = pres_ws[(size_t)n * 64 + lane];
    float tot = wave_sum_all(v);
    outp[(size_t)n * 64 + lane] = v / fmaxf(tot, 1e-6f);
}

// ---------------- launch ----------------
extern "C" void kernel_launch(void* const* d_in, const int* in_sizes, int n_in,
                              void* d_out, int out_size, void* d_ws, size_t ws_size,
                              hipStream_t stream) {
    const float* x = (const float*)d_in[0];        // [64,256,64,44]
    const float* lb = (const float*)d_in[1];       // [16,4,256]
    float* ws = (float*)d_ws;
    float* pres_ws = ws;                            // 4096 floats

    float* out = (float*)d_out;
    float* tok  = out;                     // [64,256,64]
    float* pres = out + 1048576;           // [64,64]
    float* outS = out + 1052672;           // [64,2816,64]
    float* outP = outS + 11534336;         // [64,2816,64]

    routing_kernel<<<dim3(GG, NN), 512, 0, stream>>>(
        x, lb, pres_ws, (float4*)outS, (float4*)outP, tok);
    presence_kernel<<<NN, 64, 0, stream>>>(pres_ws, pres);
}

// Round 7
// 329.385 us; speedup vs baseline: 2.3240x; 1.0182x over previous
//
#include <hip/hip_runtime.h>
#include <math.h>

// ---------------- problem constants ----------------
#define GG   16      // stripes
#define KK   4       // latents per stripe
#define NN   64      // batch
#define CC   256     // channels
#define SHH  4       // stripe height
#define WW   44      // width
#define PP   176     // pixels per stripe
#define HWSZ 2816    // 64*44
#define CHW  720896  // CC*HWSZ
#define TOPKK 22     // int(176*0.125)

#define NSTAGE_CH 160            // channels staged in LDS as bf16 (waves 0..4)
// dynamic LDS layout (bytes):
//   pd   [4][176] float4 : 0      .. 11264
//   pnf  [4][176] float2 : 11264  .. 16896
//   lbn  [256]    float4 : 16896  .. 20992
//   red  24 floats       : 20992  .. 21088
//   xst  [160][176] u16  : 21088  .. 77408
#define SMEM_BYTES 77408

// ---------------- DPP wave64 ops (VALU pipe) ----------------
template<int CTRL, int RMASK>
__device__ __forceinline__ float dpp0(float v) {
    return __int_as_float(__builtin_amdgcn_update_dpp(
        0, __float_as_int(v), CTRL, RMASK, 0xF, true));
}
__device__ __forceinline__ float nbrL(float v) { return dpp0<0x138, 0xF>(v); } // wave_shr1
__device__ __forceinline__ float nbrR(float v) { return dpp0<0x130, 0xF>(v); } // wave_shl1

// sum of all 64 lanes; result valid on lane 63 only
__device__ __forceinline__ float wave_sum63(float v) {
    v += dpp0<0x111, 0xF>(v);
    v += dpp0<0x112, 0xF>(v);
    v += dpp0<0x114, 0xF>(v);
    v += dpp0<0x118, 0xF>(v);
    v += dpp0<0x142, 0xA>(v);   // bcast15 into rows 1,3
    v += dpp0<0x143, 0xC>(v);   // bcast31 into rows 2,3
    return v;
}
__device__ __forceinline__ float bcast63(float v) {
    return __int_as_float(__builtin_amdgcn_readlane(__float_as_int(v), 63));
}
__device__ __forceinline__ float wave_sum_all(float v) { return bcast63(wave_sum63(v)); }

// max over 64 lanes, broadcast; requires true max >= 0 (zero-fill safe)
__device__ __forceinline__ float wave_max_nn(float v) {
    v = fmaxf(v, dpp0<0x111, 0xF>(v));
    v = fmaxf(v, dpp0<0x112, 0xF>(v));
    v = fmaxf(v, dpp0<0x114, 0xF>(v));
    v = fmaxf(v, dpp0<0x118, 0xF>(v));
    v = fmaxf(v, dpp0<0x142, 0xA>(v));
    v = fmaxf(v, dpp0<0x143, 0xC>(v));
    return bcast63(v);
}

__device__ __forceinline__ unsigned short bf16rne(float f) {
    unsigned u = __float_as_uint(f);
    u += 0x7FFFu + ((u >> 16) & 1u);
    return (unsigned short)(u >> 16);
}

// ---------------- fused routing + token kernel ----------------
// grid (GG, NN), 512 threads = 8 waves; wave w owns channels [w*32, w*32+32).
// NEW vs round-6: x is staged to LDS as bf16 for channels 0..159 during the
// main loop, so the token phase re-reads only 96 channels from global.
// This cuts ~110 MB of L2/L3 read traffic per dispatch (theory: the kernel
// is pinned by a ~3.5 TB/s memory-system ceiling, not latency or VALU).
// pd shrunk 8->4 buffers (waves 4-7 RMW-add after an extra barrier) to make
// LDS room; 77.4 KB dynamic LDS -> 2 blocks/CU (16 waves).
__global__ __launch_bounds__(512, 2) void routing_kernel(
    const float* __restrict__ x, const float* __restrict__ lb_raw,
    float* __restrict__ pres_ws,
    float4* __restrict__ outS, float4* __restrict__ outP,
    float* __restrict__ tok_out) {
    const int g = blockIdx.x;
    const int n = blockIdx.y;
    const int tid = threadIdx.x;
    const int w = __builtin_amdgcn_readfirstlane(tid >> 6);
    const int lane = tid & 63;
    const bool al = lane < WW;

    extern __shared__ char smem_raw[];
    float4* pd      = (float4*)smem_raw;                  // [4][PP]
    float2* pnf     = (float2*)(smem_raw + 11264);        // [4][PP]
    float4* lbn_lds = (float4*)(smem_raw + 16896);        // [CC]
    float*  redA    = (float*)(smem_raw + 20992);         // 4
    float*  redB    = redA + 4;                           // 4
    float*  zred    = redB + 4;                           // [4][4]
    unsigned short* xst = (unsigned short*)(smem_raw + 21088); // [NSTAGE_CH][PP]
    float4* sup4 = pd + 1 * PP;          // reused after reduction
    float4* pw4  = pd + 2 * PP;
    float4* pwT  = pd + 3 * PP;          // pwT[j*44+l] = pw[4*l+j]

    // ---- basis norm: wave k (0..3) normalizes latent (g,k) into LDS ----
    if (w < 4) {
        const float* row = lb_raw + ((size_t)g * KK + w) * CC;
        float v0 = row[lane], v1 = row[lane + 64], v2 = row[lane + 128], v3 = row[lane + 192];
        float ss = v0 * v0 + v1 * v1 + v2 * v2 + v3 * v3;
        float tot = wave_sum_all(ss);
        float sc = (1.0f / 9.0f) / fmaxf(sqrtf(tot), 1e-12f);
        float* dst = (float*)lbn_lds;
        dst[lane * 4 + w]         = v0 * sc;
        dst[(lane + 64) * 4 + w]  = v1 * sc;
        dst[(lane + 128) * 4 + w] = v2 * sc;
        dst[(lane + 192) * 4 + w] = v3 * sc;
    }
    __syncthreads();

    const float* xb = x + (size_t)n * CHW + g * PP;
    const int c0 = w * 32;
    const bool stager = (w < 5);     // waves 0..4 stage channels 0..159

    float4 dk[4];
    float nr[4] = {0, 0, 0, 0}, fe[4] = {0, 0, 0, 0};
    #pragma unroll
    for (int s = 0; s < 4; ++s) dk[s] = make_float4(0, 0, 0, 0);

    // prefetch depth 3: channels i (cur), i+1, i+2 in flight
    const float* xp = xb + (size_t)c0 * HWSZ + lane;
    float c0r = 0, c1r = 0, c2r = 0, c3r = 0;
    float n0r = 0, n1r = 0, n2r = 0, n3r = 0;
    float m0r = 0, m1r = 0, m2r = 0, m3r = 0;
    if (al) {
        c0r = xp[0]; c1r = xp[44]; c2r = xp[88]; c3r = xp[132];
        n0r = xp[HWSZ]; n1r = xp[HWSZ + 44]; n2r = xp[HWSZ + 88]; n3r = xp[HWSZ + 132];
        m0r = xp[2 * HWSZ]; m1r = xp[2 * HWSZ + 44]; m2r = xp[2 * HWSZ + 88]; m3r = xp[2 * HWSZ + 132];
    }
    xp += 3 * HWSZ;
    #pragma unroll 1
    for (int i = 0; i < 32; ++i) {
        float f0 = 0, f1 = 0, f2 = 0, f3 = 0;
        if (i < 29 && al) { f0 = xp[0]; f1 = xp[44]; f2 = xp[88]; f3 = xp[132]; }
        xp += HWSZ;
        float4 lbv = lbn_lds[c0 + i];   // wave-uniform -> LDS broadcast
        // stage this channel to LDS as bf16 (pixel p = s*44+lane)
        if (stager && al) {
            unsigned short* xrow = xst + (size_t)(c0 + i) * PP + lane;
            xrow[0]   = bf16rne(c0r);
            xrow[44]  = bf16rne(c1r);
            xrow[88]  = bf16rne(c2r);
            xrow[132] = bf16rne(c3r);
        }
        fe[0] += c0r * c0r; fe[1] += c1r * c1r; fe[2] += c2r * c2r; fe[3] += c3r * c3r;
        float h0 = c0r + nbrL(c0r) + nbrR(c0r);
        float h1 = c1r + nbrL(c1r) + nbrR(c1r);
        float h2 = c2r + nbrL(c2r) + nbrR(c2r);
        float h3 = c3r + nbrL(c3r) + nbrR(c3r);
        // raw 3x3 sums (1/9 folded into lbv; nrm fixed via inv=72/sqrt)
        float p0 = h0 + h1;          // row -1 zero pad
        float p1 = p0 + h2;
        float t23 = h2 + h3;
        float p2 = h1 + t23;
        float p3 = t23;              // row 4 zero pad
        nr[0] += p0 * p0; nr[1] += p1 * p1; nr[2] += p2 * p2; nr[3] += p3 * p3;
        dk[0].x += p0 * lbv.x; dk[0].y += p0 * lbv.y; dk[0].z += p0 * lbv.z; dk[0].w += p0 * lbv.w;
        dk[1].x += p1 * lbv.x; dk[1].y += p1 * lbv.y; dk[1].z += p1 * lbv.z; dk[1].w += p1 * lbv.w;
        dk[2].x += p2 * lbv.x; dk[2].y += p2 * lbv.y; dk[2].z += p2 * lbv.z; dk[2].w += p2 * lbv.w;
        dk[3].x += p3 * lbv.x; dk[3].y += p3 * lbv.y; dk[3].z += p3 * lbv.z; dk[3].w += p3 * lbv.w;
        c0r = n0r; c1r = n1r; c2r = n2r; c3r = n3r;
        n0r = m0r; n1r = m1r; n2r = m2r; n3r = m3r;
        m0r = f0; m1r = f1; m2r = f2; m3r = f3;
    }
    // ---- two-step partial write: waves 0-3 write, then waves 4-7 RMW-add ----
    if (w < 4 && al) {
        #pragma unroll
        for (int s = 0; s < 4; ++s) {
            pd[w * PP + s * 44 + lane]  = dk[s];
            pnf[w * PP + s * 44 + lane] = make_float2(nr[s], fe[s]);
        }
    }
    __syncthreads();
    if (w >= 4 && al) {
        const int wb = (w - 4) * PP;
        #pragma unroll
        for (int s = 0; s < 4; ++s) {
            const int idx = wb + s * 44 + lane;
            float4 a = pd[idx];
            a.x += dk[s].x; a.y += dk[s].y; a.z += dk[s].z; a.w += dk[s].w;
            pd[idx] = a;
            float2 b = pnf[idx];
            b.x += nr[s]; b.y += fe[s];
            pnf[idx] = b;
        }
    }
    __syncthreads();

    // ---- cross-wave reduction (4 buffers) into slot 0 ----
    if (tid < PP) {
        float4 a = pd[tid];
        #pragma unroll
        for (int ww = 1; ww < 4; ++ww) {
            float4 b = pd[ww * PP + tid];
            a.x += b.x; a.y += b.y; a.z += b.z; a.w += b.w;
        }
        pd[tid] = a;
    } else if (tid >= 256 && tid < 256 + PP) {
        const int p = tid - 256;
        float2 a = pnf[p];
        #pragma unroll
        for (int ww = 1; ww < 4; ++ww) {
            float2 b = pnf[ww * PP + p];
            a.x += b.x; a.y += b.y;
        }
        pnf[p] = a;
    }
    __syncthreads();

    // ---- finalize (8 waves redundant; waves 0..3 write) ----
    const int s4 = w & 3;
    const int pix = s4 * 44 + (al ? lane : 0);
    float4 dv = pd[pix];
    float2 nf = pnf[pix];
    float nrm = nf.x;
    float fev = nf.y * (1.0f / 256.0f);

    float fmw = wave_max_nn(al ? fev : 0.0f);
    if (w < 4 && lane == 0) redA[s4] = fmw;
    __syncthreads();
    float femax = fmaxf(fmaxf(redA[0], redA[1]), fmaxf(redA[2], redA[3]));
    float den = fmaxf(femax, 1e-6f);
    bool pa = al && ((fev / den) > 0.05f);
    unsigned long long bl = __ballot((int)pa);
    if (w < 4 && lane == 0) redB[s4] = (float)__popcll(bl);
    __syncthreads();
    float cnt = redB[0] + redB[1] + redB[2] + redB[3];
    float actv = pa ? 1.0f : 0.0f;
    if (cnt <= 0.0f) actv = (al && (fev > 0.0f)) ? 1.0f : 0.0f;

    float inv = 72.0f / fmaxf(sqrtf(nrm), 9e-12f);   // 8/TEMP on raw 3x3 sums
    float L0 = dv.x * inv, L1 = dv.y * inv, L2 = dv.z * inv, L3 = dv.w * inv;
    float mx = fmaxf(fmaxf(L0, L1), fmaxf(L2, L3));
    float e0 = expf(L0 - mx), e1 = expf(L1 - mx), e2 = expf(L2 - mx), e3 = expf(L3 - mx);
    float esum = e0 + e1 + e2 + e3;
    float sc = actv / esum;
    float s0 = e0 * sc, s1 = e1 * sc, s2 = e2 * sc, s3 = e3 * sc;

    float z0 = wave_sum63(s0), z1 = wave_sum63(s1), z2 = wave_sum63(s2), z3 = wave_sum63(s3);
    if (w < 4 && lane == 63) {
        zred[s4 * 4 + 0] = z0; zred[s4 * 4 + 1] = z1;
        zred[s4 * 4 + 2] = z2; zred[s4 * 4 + 3] = z3;
    }
    __syncthreads();
    float Z0 = zred[0] + zred[4] + zred[8]  + zred[12];
    float Z1 = zred[1] + zred[5] + zred[9]  + zred[13];
    float Z2 = zred[2] + zred[6] + zred[10] + zred[14];
    float Z3 = zred[3] + zred[7] + zred[11] + zred[15];
    float q0 = s0 / fmaxf(Z0, 1e-6f);
    float q1 = s1 / fmaxf(Z1, 1e-6f);
    float q2 = s2 / fmaxf(Z2, 1e-6f);
    float q3 = s3 / fmaxf(Z3, 1e-6f);

    if (w < 4 && al) {
        float4 qv = make_float4(q0, q1, q2, q3);
        sup4[pix] = make_float4(s0, s1, s2, s3);
        pw4[pix]  = qv;
        pwT[(pix & 3) * 44 + (pix >> 2)] = qv;   // transpose for token phase
    }
    __syncthreads();
    // After this barrier sup4/pw4/pwT/xst are final; everything below only
    // READS them, so no further __syncthreads is required.

    // ---- top-22 presence: waves 0..3; waves 4..7 do the full scatter ----
    if (w < 4) {
        const float* supf = (const float*)sup4;
        const int k = w;
        float v0 = supf[lane * 4 + k];
        float v1 = supf[(lane + 64) * 4 + k];
        float v2 = (lane < PP - 128) ? supf[(lane + 128) * 4 + k] : -1e30f;
        float tks = 0.0f;
        for (int it = 0; it < TOPKK; ++it) {
            float lm = fmaxf(v0, fmaxf(v1, v2));
            float M = wave_max_nn(lm);
            tks += M;
            unsigned long long mk = __ballot((int)(lm == M));
            int src = __ffsll(mk) - 1;
            if (lane == src) {
                if (v0 == M)      v0 = -1e30f;
                else if (v1 == M) v1 = -1e30f;
                else              v2 = -1e30f;
            }
        }
        if (lane == 0) pres_ws[(size_t)n * 64 + g * KK + k] = tks * (1.0f / (float)TOPKK);
    } else {
        // ---- direct scatter: block owns output pixels [g*176, g*176+176) ----
        const size_t obase = ((size_t)n * HWSZ + (size_t)g * PP) * 16;
        const float4 z = make_float4(0, 0, 0, 0);
        const int t0i = tid - 256;   // 0..255, PP*16/256 = 11 iters
        #pragma unroll 1
        for (int m = 0; m < 11; ++m) {
            const int j = t0i + m * 256;
            const int px = j >> 4, q = j & 15;
            const bool hit = (q == g);
            outS[obase + j] = hit ? sup4[px] : z;
            outP[obase + j] = hit ? pw4[px]  : z;
        }
    }

    // ---- fused token phase: wave w reduces tokens for channels [c0, c0+32) ----
    // lane l<44 owns pixels 4l..4l+3; pw pre-transposed in pwT.
    // Waves 0..4 read x from the bf16 LDS stage; waves 5..7 re-read global.
    {
        float4 pwa = make_float4(0, 0, 0, 0), pwb = pwa, pwc = pwa, pwd = pwa;
        if (al) {
            pwa = pwT[lane];        // pw of pixel 4l+0
            pwb = pwT[44 + lane];   // 4l+1
            pwc = pwT[88 + lane];   // 4l+2
            pwd = pwT[132 + lane];  // 4l+3
        }
        float* tokg = tok_out + ((size_t)n * CC + c0) * 64 + g * KK;

        if (stager) {
            // LDS bf16 path
            const unsigned short* xr = xst + (size_t)c0 * PP + 4 * (al ? lane : 0);
            #pragma unroll 1
            for (int i = 0; i < 32; ++i) {
                float b0 = 0, b1 = 0, b2 = 0, b3 = 0;
                if (al) {
                    ushort4 v = *(const ushort4*)(xr + (size_t)i * PP);
                    b0 = __uint_as_float((unsigned)v.x << 16);
                    b1 = __uint_as_float((unsigned)v.y << 16);
                    b2 = __uint_as_float((unsigned)v.z << 16);
                    b3 = __uint_as_float((unsigned)v.w << 16);
                }
                float t0 = b0 * pwa.x + b1 * pwb.x + b2 * pwc.x + b3 * pwd.x;
                float t1 = b0 * pwa.y + b1 * pwb.y + b2 * pwc.y + b3 * pwd.y;
                float t2 = b0 * pwa.z + b1 * pwb.z + b2 * pwc.z + b3 * pwd.z;
                float t3 = b0 * pwa.w + b1 * pwb.w + b2 * pwc.w + b3 * pwd.w;
                t0 = wave_sum63(t0); t1 = wave_sum63(t1); t2 = wave_sum63(t2); t3 = wave_sum63(t3);
                if (lane == 63) {
                    *(float4*)(tokg + (size_t)i * 64) = make_float4(t0, t1, t2, t3);
                }
            }
        } else {
            // global re-read path (channels 160..255), depth-3 prefetch
            const float4* xq4 = (const float4*)(xb + (size_t)c0 * HWSZ) + lane;
            float4 tA = make_float4(0, 0, 0, 0), tB = tA, tC = tA;
            if (al) { tA = xq4[0]; tB = xq4[704]; tC = xq4[1408]; }
            xq4 += 3 * 704;
            #pragma unroll 1
            for (int i = 0; i < 32; ++i) {
                float4 tF = make_float4(0, 0, 0, 0);
                if (i < 29 && al) tF = xq4[0];
                xq4 += 704;
                float t0 = tA.x * pwa.x + tA.y * pwb.x + tA.z * pwc.x + tA.w * pwd.x;
                float t1 = tA.x * pwa.y + tA.y * pwb.y + tA.z * pwc.y + tA.w * pwd.y;
                float t2 = tA.x * pwa.z + tA.y * pwb.z + tA.z * pwc.z + tA.w * pwd.z;
                float t3 = tA.x * pwa.w + tA.y * pwb.w + tA.z * pwc.w + tA.w * pwd.w;
                t0 = wave_sum63(t0); t1 = wave_sum63(t1); t2 = wave_sum63(t2); t3 = wave_sum63(t3);
                if (lane == 63) {
                    *(float4*)(tokg + (size_t)i * 64) = make_float4(t0, t1, t2, t3);
                }
                tA = tB; tB = tC; tC = tF;
            }
        }
    }
}

// ---------------- presence normalization ----------------
__global__ __launch_bounds__(64) void presence_kernel(
    const float* __restrict__ pres_ws, float* __restrict__ outp) {
    const int n = blockIdx.x;
    const int lane = threadIdx.x;
    float v = pres_ws[(size_t)n * 64 + lane];
    float tot = wave_sum_all(v);
    outp[(size_t)n * 64 + lane] = v / fmaxf(tot, 1e-6f);
}

// ---------------- launch ----------------
extern "C" void kernel_launch(void* const* d_in, const int* in_sizes, int n_in,
                              void* d_out, int out_size, void* d_ws, size_t ws_size,
                              hipStream_t stream) {
    const float* x = (const float*)d_in[0];        // [64,256,64,44]
    const float* lb = (const float*)d_in[1];       // [16,4,256]
    float* ws = (float*)d_ws;
    float* pres_ws = ws;                            // 4096 floats

    float* out = (float*)d_out;
    float* tok  = out;                     // [64,256,64]
    float* pres = out + 1048576;           // [64,64]
    float* outS = out + 1052672;           // [64,2816,64]
    float* outP = outS + 11534336;         // [64,2816,64]

    static bool attr_set = false;
    if (!attr_set) {
        hipFuncSetAttribute((const void*)routing_kernel,
                            hipFuncAttributeMaxDynamicSharedMemorySize,
                            SMEM_BYTES);
        attr_set = true;
    }

    routing_kernel<<<dim3(GG, NN), 512, SMEM_BYTES, stream>>>(
        x, lb, pres_ws, (float4*)outS, (float4*)outP, tok);
    presence_kernel<<<NN, 64, 0, stream>>>(pres_ws, pres);
}